// Round 1
// baseline (665.302 us; speedup 1.0000x reference)
//
#include <hip/hip_runtime.h>

#define NV 200000
#define COUT 128

typedef __attribute__((ext_vector_type(8))) short sh8;
typedef __attribute__((ext_vector_type(4))) float f32x4;
typedef __attribute__((ext_vector_type(4))) unsigned short us4;

__device__ inline unsigned short f2bf(float f) {
  unsigned int u = __builtin_bit_cast(unsigned int, f);
  u += 0x7FFFu + ((u >> 16) & 1u);
  return (unsigned short)(u >> 16);
}
__device__ inline float bf2f(unsigned short h) {
  unsigned int u = ((unsigned int)h) << 16;
  return __builtin_bit_cast(float, u);
}

// ---------------------------------------------------------------------------
// Pre-pass: feats f32 -> bf16 (with zero pad row N), zero the stat buffers.
// ---------------------------------------------------------------------------
__global__ void cvt_feats(const float* __restrict__ f,
                          unsigned short* __restrict__ fb,
                          float* __restrict__ stats /*1024 floats*/) {
  const long i = (long)blockIdx.x * blockDim.x + threadIdx.x;
  const long totq = (long)NV * 64 / 4;  // 3,200,000 quads
  if (i < totq) {
    const f32x4 v = *(const f32x4*)(f + i * 4);
    us4 o;
#pragma unroll
    for (int j = 0; j < 4; ++j) o[j] = f2bf(v[j]);
    *(us4*)(fb + i * 4) = o;
  } else if (i < totq + 16) {
    const long j = i - totq;
    *(us4*)(fb + (long)NV * 64 + j * 4) = (us4){0, 0, 0, 0};
  } else if (i < totq + 16 + 256) {
    const long j = i - totq - 16;
    *(f32x4*)(stats + j * 4) = (f32x4){0.f, 0.f, 0.f, 0.f};
  }
}

// ---------------------------------------------------------------------------
// Weight transpose+convert: W[k][c][d] f32  ->  Wt[k][d][c] bf16
// segments: T1 (9*128*64), T2 (9*128*64), T12 (9*128*128), T3 (9*128*128)
// ---------------------------------------------------------------------------
__global__ void cvt_w(const float* __restrict__ W1, const float* __restrict__ W12,
                      const float* __restrict__ W2, const float* __restrict__ W3,
                      unsigned short* __restrict__ T1, unsigned short* __restrict__ T12,
                      unsigned short* __restrict__ T2, unsigned short* __restrict__ T3) {
  int i = blockIdx.x * 256 + threadIdx.x;
  const float* src;
  unsigned short* dst;
  int cin;
  if (i < 73728) {
    src = W1; dst = T1; cin = 64;
  } else if (i < 147456) {
    src = W2; dst = T2; cin = 64; i -= 73728;
  } else if (i < 294912) {
    src = W12; dst = T12; cin = 128; i -= 147456;
  } else if (i < 442368) {
    src = W3; dst = T3; cin = 128; i -= 294912;
  } else {
    return;
  }
  const int c = i % cin;
  const int rest = i / cin;
  const int d = rest % 128;
  const int k = rest / 128;
  dst[i] = f2bf(src[((size_t)(k * cin + c)) * 128 + d]);
}

// ---------------------------------------------------------------------------
// Gathered-GEMM conv:  Y[n,d] = lrelu( sum_k sum_c A[nbr[k][n], c] * W[k][c][d] )
// A: (NV+1) x CIN bf16 (row NV = zeros).  Wt: [9][128][CIN] bf16.
// Also accumulates per-channel sum / sumsq of the lrelu output (for BN).
// Block = 256 thr (4 waves), 64 rows. Wave w -> cols [32w, 32w+32), rows 0..63.
// ---------------------------------------------------------------------------
template <int CIN>
__global__ __launch_bounds__(256) void conv_k(
    const unsigned short* __restrict__ A, const unsigned short* __restrict__ Wt,
    const int* __restrict__ nbr, unsigned short* __restrict__ Y,
    float* __restrict__ gsum, float* __restrict__ gsq) {
  constexpr int BM = 64;
  constexpr int CHUNKS = CIN / 8;  // 16B chunks per row
  __shared__ unsigned short Atile[2][BM * CIN];
  __shared__ int sidx[9 * BM];
  __shared__ float ssum[COUT];
  __shared__ float ssq[COUT];

  const int tid = threadIdx.x;
  const int lane = tid & 63;
  const int wv = tid >> 6;
  const int row0 = blockIdx.x * BM;

  for (int i = tid; i < 9 * BM; i += 256)
    sidx[i] = nbr[(i >> 6) * NV + row0 + (i & 63)];
  __syncthreads();

  f32x4 acc[4][2];
#pragma unroll
  for (int rt = 0; rt < 4; ++rt)
#pragma unroll
    for (int ct = 0; ct < 2; ++ct) acc[rt][ct] = (f32x4){0.f, 0.f, 0.f, 0.f};

  const int l15 = lane & 15;
  const int l4 = lane >> 4;

  // Stage 64 rows x CIN bf16 into LDS (linear dest, XOR-swizzled source so
  // ds_read_b128 fragment reads are bank-conflict-light). Wave w stages rows
  // [16w, 16w+16).
  auto stage = [&](int buf, int k) {
    constexpr int RPI = 64 / CHUNKS;  // rows per 1KB issue (8 or 4)
    const int jj = lane % CHUNKS;
    const int rr = lane / CHUNKS;
#pragma unroll
    for (int i = 0; i < 16 / RPI; ++i) {
      const int r = wv * 16 + i * RPI + rr;
      const long src = (long)sidx[k * BM + r] * CIN + (long)((jj ^ (r & 7)) * 8);
      const unsigned short* gp = A + src;
      unsigned short* lp = &Atile[buf][(wv * 16 + i * RPI) * CIN];
      __builtin_amdgcn_global_load_lds(
          (const __attribute__((address_space(1))) unsigned int*)gp,
          (__attribute__((address_space(3))) unsigned int*)lp, 16, 0, 0);
    }
  };

  stage(0, 0);
  __syncthreads();

  for (int k = 0; k < 9; ++k) {
    const int buf = k & 1;
    if (k < 8) stage(buf ^ 1, k + 1);
#pragma unroll
    for (int s = 0; s < CIN / 32; ++s) {
      const int j = s * 4 + l4;
      sh8 bfr[2];
#pragma unroll
      for (int ct = 0; ct < 2; ++ct) {
        const int d = wv * 32 + ct * 16 + l15;
        bfr[ct] = *(const sh8*)(Wt + ((size_t)(k * COUT + d) * CIN + s * 32 + l4 * 8));
      }
#pragma unroll
      for (int rt = 0; rt < 4; ++rt) {
        const int r = rt * 16 + l15;
        const sh8 af = *(const sh8*)(&Atile[buf][r * CIN + ((j ^ (r & 7)) * 8)]);
#pragma unroll
        for (int ct = 0; ct < 2; ++ct)
          acc[rt][ct] =
              __builtin_amdgcn_mfma_f32_16x16x32_bf16(af, bfr[ct], acc[rt][ct], 0, 0, 0);
      }
    }
    __syncthreads();
  }

  // Epilogue: LeakyReLU, bf16 store, per-channel partial sums.
#pragma unroll
  for (int ct = 0; ct < 2; ++ct) {
    const int col = wv * 32 + ct * 16 + l15;
    float sp = 0.f, qp = 0.f;
#pragma unroll
    for (int rt = 0; rt < 4; ++rt) {
#pragma unroll
      for (int q = 0; q < 4; ++q) {
        float v = acc[rt][ct][q];
        v = (v >= 0.f) ? v : 0.01f * v;
        const int grow = row0 + rt * 16 + l4 * 4 + q;
        Y[(size_t)grow * COUT + col] = f2bf(v);
        sp += v;
        qp += v * v;
      }
    }
    sp += __shfl_xor(sp, 16);
    sp += __shfl_xor(sp, 32);
    qp += __shfl_xor(qp, 16);
    qp += __shfl_xor(qp, 32);
    if (l4 == 0) {  // exactly one writer per column in the block
      ssum[col] = sp;
      ssq[col] = qp;
    }
  }
  __syncthreads();
  if (tid < COUT) {
    atomicAdd(&gsum[tid], ssum[tid]);
    atomicAdd(&gsq[tid], ssq[tid]);
  }
}

// ---------------------------------------------------------------------------
// BN stats -> per-channel scale/bias:  a = g*rsqrt(var+eps), b = beta - mean*a
// ---------------------------------------------------------------------------
__global__ void stats_k(const float* __restrict__ sum, const float* __restrict__ sq,
                        const float* __restrict__ g, const float* __restrict__ bt,
                        float* __restrict__ a_out, float* __restrict__ b_out) {
  const int t = threadIdx.x;
  if (t < COUT) {
    const float m = sum[t] * (1.0f / (float)NV);
    const float v = sq[t] * (1.0f / (float)NV) - m * m;
    const float a = g[t] * rsqrtf(v + 1e-5f);
    a_out[t] = a;
    b_out[t] = bt[t] - m * a;
  }
}

// ---------------------------------------------------------------------------
// In-place normalize (bf16), zero pad row NV.
// ---------------------------------------------------------------------------
__global__ void affine_k(unsigned short* __restrict__ Y, const float* __restrict__ a,
                         const float* __restrict__ b) {
  const long i = (long)blockIdx.x * blockDim.x + threadIdx.x;
  const long tot = (long)(NV + 1) * COUT / 8;
  if (i >= tot) return;
  const long base = i * 8;
  const int row = (int)(base >> 7);
  const int c0 = (int)(base & 127);
  sh8 o;
  if (row >= NV) {
    o = (sh8){0, 0, 0, 0, 0, 0, 0, 0};
  } else {
    const sh8 v = *(const sh8*)(Y + base);
    const f32x4 aL = *(const f32x4*)(a + c0);
    const f32x4 aH = *(const f32x4*)(a + c0 + 4);
    const f32x4 bL = *(const f32x4*)(b + c0);
    const f32x4 bH = *(const f32x4*)(b + c0 + 4);
#pragma unroll
    for (int j = 0; j < 4; ++j) {
      const float f0 = bf2f((unsigned short)v[j]) * aL[j] + bL[j];
      const float f1 = bf2f((unsigned short)v[4 + j]) * aH[j] + bH[j];
      o[j] = (short)f2bf(f0);
      o[4 + j] = (short)f2bf(f1);
    }
  }
  *(sh8*)(Y + base) = o;
}

// ---------------------------------------------------------------------------
// out = normalize(y3) + ysc   (f32 output)
// ---------------------------------------------------------------------------
__global__ void final_k(const unsigned short* __restrict__ y3,
                        const unsigned short* __restrict__ ysc,
                        const float* __restrict__ a, const float* __restrict__ b,
                        float* __restrict__ out) {
  const long i = (long)blockIdx.x * blockDim.x + threadIdx.x;
  const long tot = (long)NV * COUT / 8;
  if (i >= tot) return;
  const long base = i * 8;
  const int c0 = (int)(base & 127);
  const sh8 v3 = *(const sh8*)(y3 + base);
  const sh8 vs = *(const sh8*)(ysc + base);
  const f32x4 aL = *(const f32x4*)(a + c0);
  const f32x4 aH = *(const f32x4*)(a + c0 + 4);
  const f32x4 bL = *(const f32x4*)(b + c0);
  const f32x4 bH = *(const f32x4*)(b + c0 + 4);
  f32x4 oL, oH;
#pragma unroll
  for (int j = 0; j < 4; ++j) {
    oL[j] = bf2f((unsigned short)v3[j]) * aL[j] + bL[j] + bf2f((unsigned short)vs[j]);
    oH[j] = bf2f((unsigned short)v3[4 + j]) * aH[j] + bH[j] + bf2f((unsigned short)vs[4 + j]);
  }
  *(f32x4*)(out + base) = oL;
  *(f32x4*)(out + base + 4) = oH;
}

// ---------------------------------------------------------------------------
extern "C" void kernel_launch(void* const* d_in, const int* in_sizes, int n_in,
                              void* d_out, int out_size, void* d_ws, size_t ws_size,
                              hipStream_t stream) {
  const float* feats = (const float*)d_in[0];
  const float* W1 = (const float*)d_in[1];
  const float* W12 = (const float*)d_in[2];
  const float* W2 = (const float*)d_in[3];
  const float* W3 = (const float*)d_in[4];
  const float* g0 = (const float*)d_in[5];
  const float* b0 = (const float*)d_in[6];
  const float* g02 = (const float*)d_in[7];
  const float* b02 = (const float*)d_in[8];
  const float* g1 = (const float*)d_in[9];
  const float* b1 = (const float*)d_in[10];
  const float* g2 = (const float*)d_in[11];
  const float* b2 = (const float*)d_in[12];
  const int* nbr31 = (const int*)d_in[13];
  const int* nbr13 = (const int*)d_in[14];
  float* out = (float*)d_out;

  char* ws = (char*)d_ws;
  size_t off = 0;
  auto alloc = [&](size_t bytes) {
    char* p = ws + off;
    off = (off + bytes + 255) & ~(size_t)255;
    return p;
  };

  unsigned short* fb = (unsigned short*)alloc((size_t)(NV + 1) * 64 * 2);
  unsigned short* T1 = (unsigned short*)alloc((size_t)9 * 128 * 64 * 2);
  unsigned short* T2 = (unsigned short*)alloc((size_t)9 * 128 * 64 * 2);
  unsigned short* T12 = (unsigned short*)alloc((size_t)9 * 128 * 128 * 2);
  unsigned short* T3 = (unsigned short*)alloc((size_t)9 * 128 * 128 * 2);
  unsigned short* y1 = (unsigned short*)alloc((size_t)(NV + 1) * COUT * 2);
  unsigned short* ysc = (unsigned short*)alloc((size_t)(NV + 1) * COUT * 2);
  unsigned short* y2 = (unsigned short*)alloc((size_t)(NV + 1) * COUT * 2);
  float* stats = (float*)alloc(1024 * 4);
  float* ab = (float*)alloc(1024 * 4);
  unsigned short* y3 = y1;  // y1 is dead after conv1_2 consumes it

  float* sum0 = stats + 0, *sq0 = stats + 128;
  float* sum1 = stats + 256, *sq1 = stats + 384;
  float* sum2 = stats + 512, *sq2 = stats + 640;
  float* sum3 = stats + 768, *sq3 = stats + 896;
  float* a0 = ab + 0, *bb0 = ab + 128;
  float* a1 = ab + 256, *bb1 = ab + 384;
  float* a2 = ab + 512, *bb2 = ab + 640;
  float* a3 = ab + 768, *bb3 = ab + 896;

  const int convGrid = NV / 64;            // 3125
  const int affGrid = (3200016 + 255) / 256;  // (NV+1)*128/8 octets
  const int finGrid = (3200000 + 255) / 256;  // NV*128/8 octets

  cvt_feats<<<(3200272 + 255) / 256, 256, 0, stream>>>(feats, fb, stats);
  cvt_w<<<(442368 + 255) / 256, 256, 0, stream>>>(W1, W12, W2, W3, T1, T12, T2, T3);

  // shortcut branch, layer 1
  conv_k<64><<<convGrid, 256, 0, stream>>>(fb, T1, nbr31, y1, sum0, sq0);
  stats_k<<<1, 128, 0, stream>>>(sum0, sq0, g0, b0, a0, bb0);
  affine_k<<<affGrid, 256, 0, stream>>>(y1, a0, bb0);
  // shortcut branch, layer 2
  conv_k<128><<<convGrid, 256, 0, stream>>>(y1, T12, nbr13, ysc, sum1, sq1);
  stats_k<<<1, 128, 0, stream>>>(sum1, sq1, g02, b02, a1, bb1);
  affine_k<<<affGrid, 256, 0, stream>>>(ysc, a1, bb1);
  // resA branch, layer 1
  conv_k<64><<<convGrid, 256, 0, stream>>>(fb, T2, nbr13, y2, sum2, sq2);
  stats_k<<<1, 128, 0, stream>>>(sum2, sq2, g1, b1, a2, bb2);
  affine_k<<<affGrid, 256, 0, stream>>>(y2, a2, bb2);
  // resA branch, layer 2
  conv_k<128><<<convGrid, 256, 0, stream>>>(y2, T3, nbr31, y3, sum3, sq3);
  stats_k<<<1, 128, 0, stream>>>(sum3, sq3, g2, b2, a3, bb3);
  // residual add (+ final normalize fused)
  final_k<<<finGrid, 256, 0, stream>>>(y3, ysc, a3, bb3, out);
}